// Round 2
// baseline (1531.618 us; speedup 1.0000x reference)
//
#include <hip/hip_runtime.h>

// 2-layer LSTM encoder, B=128, T=1024, F=1, HID=128, EMB=64.
// R11 = hybrid pipe split (R10 null result -> step is pipe-throughput-bound:
//   ~64% of the 1690cy step is matrix-pipe occupancy; 15/16 of it redundant
//   rows since batch=1/block).
//   - waves 4..7: layer-1 on MFMA pipe, unchanged from R10 (32 MFMAs/wave,
//     depth-4 chains) but ew spread to 32 lanes (1 cell/lane, h = quad&1)
//   - waves 0..3: layer-2 moved OFF the MFMA pipe onto VALU v_dot2_f32_f16:
//     each lane owns one gate-row (gate j=l&3, cell 16*idx+(l>>2)); weights
//     (128 ih + 64 hh halves = 96 VGPRs packed) in registers; h1/h2 read as
//     uniform-address LDS broadcasts (24 ds_read_b128); 96 fdot2/step.
//     ew: per-lane activation via tanh(x)=2*sigmoid(2x)-1 constant trick
//     (2 trans), DPP quad_perm broadcasts gather i,f,g,o (3+1 movs), c2 kept
//     redundantly in all 4 quad lanes, 1 store lane. 4 trans/cell vs 10.
//   - WB[32] f16x8 storage OVERLAYED between roles (L1: 32 B-frags; L2:
//     frags 0..15 = ih weights, 16..23 = hh weights) so register footprints
//     don't add across the divergent role branches.
// MFMA/VALU co-schedule across waves (m114) -> step ~ max(620cy MFMA-pipe
// from L1 waves, ~450cy VALU from L2 waves + L1 ew) instead of 1086+VALU.
// Slot audit (unchanged): h1(m) -> H1[m&1]; h2(m) -> H2[m&1];
// epilogue reads h1(1023)=H1[1], h2(1022)=H2[0].

#define TB   1024
#define HID1 128
#define EMB2 64

typedef _Float16 f16x8 __attribute__((ext_vector_type(8)));
typedef _Float16 f16x2 __attribute__((ext_vector_type(2)));
typedef float    f32x4 __attribute__((ext_vector_type(4)));

#define MFMA16(a,b,c) __builtin_amdgcn_mfma_f32_16x16x32_f16((a),(b),(c),0,0,0)

static __device__ __forceinline__ float fast_exp2(float x){
#if __has_builtin(__builtin_amdgcn_exp2f)
  return __builtin_amdgcn_exp2f(x);
#else
  return __exp2f(x);
#endif
}
static __device__ __forceinline__ float fast_rcp(float x){
#if __has_builtin(__builtin_amdgcn_rcpf)
  return __builtin_amdgcn_rcpf(x);
#else
  return 1.0f / x;
#endif
}
static __device__ __forceinline__ float sigmoid_f(float x){
  return fast_rcp(1.0f + fast_exp2(-1.44269504088896340736f * x));
}
static __device__ __forceinline__ float tanh_f(float x){
  return 1.0f - 2.0f * fast_rcp(1.0f + fast_exp2(2.88539008177792681472f * x));
}

static __device__ __forceinline__ f16x8 load_frag(const float* p){
  f16x8 r;
  #pragma unroll
  for (int j = 0; j < 8; ++j) r[j] = (_Float16)p[j];
  return r;
}

static __device__ __forceinline__ f16x2 h2at(f16x8 v, int m){
  f16x2 r; r[0] = v[2*m]; r[1] = v[2*m+1]; return r;
}

static __device__ __forceinline__ float dot2(f16x2 a, f16x2 b, float c){
#if __has_builtin(__builtin_amdgcn_fdot2)
  return __builtin_amdgcn_fdot2(a, b, c, false);
#else
  return c + (float)a[0]*(float)b[0] + (float)a[1]*(float)b[1];
#endif
}

__launch_bounds__(512, 2)
__global__ void lstm2_kernel(const float* __restrict__ x,
                             const float* __restrict__ w_ih1,
                             const float* __restrict__ w_hh1,
                             const float* __restrict__ b_ih1,
                             const float* __restrict__ b_hh1,
                             const float* __restrict__ w_ih2,
                             const float* __restrict__ w_hh2,
                             const float* __restrict__ b_ih2,
                             const float* __restrict__ b_hh2,
                             float* __restrict__ out)
{
  __shared__ __align__(16) float    xs[TB];
  __shared__ __align__(16) _Float16 H1[2][HID1];  // h1 ping-pong
  __shared__ __align__(16) _Float16 H2[2][EMB2];  // h2 ping-pong

  const int t    = threadIdx.x;   // 0..511
  const int b    = blockIdx.x;    // 0..127
  const int l    = t & 63;        // lane
  const int w    = t >> 6;        // wave 0..7
  const int col  = l & 15;
  const int quad = l >> 4;
  const int role1 = w >> 2;       // 1 = layer-1 wave (4..7), 0 = layer-2 wave (0..3)
  const int idx   = w & 3;        // index within role
  const int hh    = quad & 1;     // L1 ew half (lanes<32 active: quad 0/1)

  // ---- overlayed weight storage ----
  f16x8 WB[32];
  float biasL[4], wxL[4];          // role1: per-lane (gate g, half hh)
  float biasL2 = 0.0f;             // role2: own gate-row bias
  float c0v = -1.44269504088896340736f, aMul = 1.0f, aAdd = 0.0f;  // role2 act consts

  if (role1){
    // L1 B-fragments: all 8 gate-tiles (gate g, half h), 4 K-chunks each.
    #pragma unroll
    for (int g = 0; g < 4; ++g){
      #pragma unroll
      for (int h = 0; h < 2; ++h){
        const int fi = 2*g + h;
        const int nc = (8*g + 2*idx + h)*16 + col;
        #pragma unroll
        for (int k = 0; k < 4; ++k)
          WB[4*fi + k] = load_frag(w_hh1 + nc*HID1 + k*32 + quad*8);
      }
    }
    // per-lane bias/wx for the one cell this lane updates (half = hh)
    #pragma unroll
    for (int g = 0; g < 4; ++g){
      const int nc = (8*g + 2*idx + hh)*16 + col;
      biasL[g] = b_ih1[nc] + b_hh1[nc];
      wxL[g]   = w_ih1[nc];                    // w_ih1 is (512,1)
    }
  } else {
    // L2: lane owns gate-row r = 64*gate + cell; gate = l&3, cell = 16*idx + (l>>2).
    const int j4 = l & 3;
    const int q  = l >> 2;
    const int r  = 64*j4 + 16*idx + q;
    biasL2 = b_ih2[r] + b_hh2[r];
    if (j4 == 2){ c0v = -2.88539008177792681472f; aMul = 2.0f; aAdd = -1.0f; } // tanh gate
    #pragma unroll
    for (int c = 0; c < 16; ++c){
      f16x8 v;
      #pragma unroll
      for (int e = 0; e < 8; ++e) v[e] = (_Float16)w_ih2[r*HID1 + 8*c + e];
      WB[c] = v;
    }
    #pragma unroll
    for (int c = 0; c < 8; ++c){
      f16x8 v;
      #pragma unroll
      for (int e = 0; e < 8; ++e) v[e] = (_Float16)w_hh2[r*EMB2 + 8*c + e];
      WB[16 + c] = v;
    }
    #pragma unroll
    for (int c = 24; c < 32; ++c) WB[c] = WB[c - 24];  // keep array fully defined
  }

  // ---- x preload + state init ----
  xs[t]       = x[b * TB + t];
  xs[t + 512] = x[b * TB + t + 512];
  if (t < HID1) { H1[0][t] = (_Float16)0.0f; H1[1][t] = (_Float16)0.0f; }
  else if (t < HID1 + EMB2){
    H2[0][t-HID1] = (_Float16)0.0f; H2[1][t-HID1] = (_Float16)0.0f;
  }
  __syncthreads();

  float c1 = 0.0f, c2 = 0.0f;
  const f32x4 zacc = {0.0f, 0.0f, 0.0f, 0.0f};

  // ---- role-2 helpers: full gate-row dot + cell update ----
  auto l2gate = [&](const f16x8* pH1v, const f16x8* pH2v) -> float {
    float a0 = biasL2, a1 = 0.0f, a2 = 0.0f, a3 = 0.0f;
    #pragma unroll
    for (int c = 0; c < 16; c += 4){
      const f16x8 hA = pH1v[c+0], hB = pH1v[c+1], hC = pH1v[c+2], hD = pH1v[c+3];
      #pragma unroll
      for (int m = 0; m < 4; ++m){
        a0 = dot2(h2at(hA,m), h2at(WB[c+0],m), a0);
        a1 = dot2(h2at(hB,m), h2at(WB[c+1],m), a1);
        a2 = dot2(h2at(hC,m), h2at(WB[c+2],m), a2);
        a3 = dot2(h2at(hD,m), h2at(WB[c+3],m), a3);
      }
    }
    #pragma unroll
    for (int c = 0; c < 8; c += 4){
      const f16x8 hA = pH2v[c+0], hB = pH2v[c+1], hC = pH2v[c+2], hD = pH2v[c+3];
      #pragma unroll
      for (int m = 0; m < 4; ++m){
        a0 = dot2(h2at(hA,m), h2at(WB[16+c+0],m), a0);
        a1 = dot2(h2at(hB,m), h2at(WB[16+c+1],m), a1);
        a2 = dot2(h2at(hC,m), h2at(WB[16+c+2],m), a2);
        a3 = dot2(h2at(hD,m), h2at(WB[16+c+3],m), a3);
      }
    }
    return (a0 + a1) + (a2 + a3);
  };

  auto l2cell = [&](const f16x8* pH1v, const f16x8* pH2v) -> float {
    const float p   = l2gate(pH1v, pH2v);
    // per-lane activation: sigmoid for i,f,o; tanh via 2*sigmoid(2x)-1 for g
    const float act = __builtin_fmaf(aMul, fast_rcp(1.0f + fast_exp2(c0v * p)), aAdd);
    const int   av  = __float_as_int(act);
    const float gi  = __int_as_float(__builtin_amdgcn_mov_dpp(av, 0x00, 0xF, 0xF, true));
    const float gf  = __int_as_float(__builtin_amdgcn_mov_dpp(av, 0x55, 0xF, 0xF, true));
    const float gg  = __int_as_float(__builtin_amdgcn_mov_dpp(av, 0xAA, 0xF, 0xF, true));
    const float go  = __int_as_float(__builtin_amdgcn_mov_dpp(av, 0xFF, 0xF, 0xF, true));
    c2 = gf * c2 + gi * gg;           // redundant but identical across the quad
    return go * tanh_f(c2);
  };

  // ---- prologue: L1 step 0. h1(-1)=0 -> gates = x*w + b; no MFMA needed ----
  if (role1 && l < 32){
    const float xt = xs[0];
    float g4[4];
    #pragma unroll
    for (int g = 0; g < 4; ++g) g4[g] = __builtin_fmaf(xt, wxL[g], biasL[g]);
    c1 = sigmoid_f(g4[1]) * c1 + sigmoid_f(g4[0]) * tanh_f(g4[2]);
    const float hv = sigmoid_f(g4[3]) * tanh_f(c1);
    H1[0][32*idx + 16*hh + col] = (_Float16)hv;
  }
  __syncthreads();

  // ---- main pipelined loop: superstep s = L1(s) on waves 4-7 (MFMA) ||
  //      L2(s-1) on waves 0-3 (fdot2), one barrier. ----
  #pragma unroll 1
  for (int s = 1; s < TB; ++s){
    const int ra1 = (s + 1) & 1;       // h1(s-1) slot
    const int wa1 = s & 1;             // h1(s)   slot
    const int ra2 = s & 1;             // h2(s-2) slot
    const int wa2 = (s + 1) & 1;       // h2(s-1) slot

    if (role1){
      const f16x8* pA1 = (const f16x8*)&H1[ra1][0];
      f16x8 a1[4];
      #pragma unroll
      for (int k = 0; k < 4; ++k) a1[k] = pA1[4*k + quad];
      const float xt = xs[s];

      f32x4 acc[8];
      #pragma unroll
      for (int f = 0; f < 8; ++f) acc[f] = MFMA16(a1[0], WB[4*f], zacc);
      #pragma unroll
      for (int k = 1; k < 4; ++k){
        #pragma unroll
        for (int f = 0; f < 8; ++f) acc[f] = MFMA16(a1[k], WB[4*f + k], acc[f]);
      }
      if (l < 32){
        // C rows are identical (A rows replicated), so reg 0 is valid in any quad.
        float g4[4];
        #pragma unroll
        for (int g = 0; g < 4; ++g)
          g4[g] = acc[2*g + hh][0] + __builtin_fmaf(xt, wxL[g], biasL[g]);
        c1 = sigmoid_f(g4[1]) * c1 + sigmoid_f(g4[0]) * tanh_f(g4[2]);
        const float hv = sigmoid_f(g4[3]) * tanh_f(c1);
        H1[wa1][32*idx + 16*hh + col] = (_Float16)hv;
      }
    } else {
      const float hv = l2cell((const f16x8*)&H1[ra1][0], (const f16x8*)&H2[ra2][0]);
      if ((l & 3) == 0) H2[wa2][16*idx + (l >> 2)] = (_Float16)hv;
    }
    __syncthreads();
  }

  // ---- epilogue: L2 step TB-1 -> output.
  //      h1(1023) in H1[1]; h2(1022) in H2[0] (slot = m&1) ----
  if (!role1){
    const float hv = l2cell((const f16x8*)&H1[1][0], (const f16x8*)&H2[0][0]);
    if ((l & 3) == 0) out[b * EMB2 + 16*idx + (l >> 2)] = hv;
  }
}

extern "C" void kernel_launch(void* const* d_in, const int* in_sizes, int n_in,
                              void* d_out, int out_size, void* d_ws, size_t ws_size,
                              hipStream_t stream) {
  lstm2_kernel<<<dim3(128), dim3(512), 0, stream>>>(
      (const float*)d_in[0],   // x
      (const float*)d_in[1],   // w_ih1
      (const float*)d_in[2],   // w_hh1
      (const float*)d_in[3],   // b_ih1
      (const float*)d_in[4],   // b_hh1
      (const float*)d_in[5],   // w_ih2
      (const float*)d_in[6],   // w_hh2
      (const float*)d_in[7],   // b_ih2
      (const float*)d_in[8],   // b_hh2
      (float*)d_out);
}